// Round 17
// baseline (91.002 us; speedup 1.0000x reference)
//
#include <hip/hip_runtime.h>
#include <hip/hip_fp16.h>

// ACM-GCN graph conv, R17 (corrected zero grid).
// R16 post-mortem: octant banding null (16-edge lists -> ~2 edges/octant,
// no coherent sweep; FETCH already compulsory-only). R17:
//  - revert sort to row-only;
//  - 256-node buckets + 16384-edge scatter chunks -> WRITE ~15MB;
//  - spmm 4-quad iterations (8 rec + 8 gathers in flight) as
//    latency-vs-BW diagnostic.

#define NNODE 50000
#define NEDGE 800000
#define NBUCK 196              // 256-node buckets per graph (49999>>8 = 195)
#define CAP   5504             // slots/bucket: padded mean ~4977 + 8 sigma, %8==0
#define SORT_BLOCKS (2 * NBUCK)          // 392
#define GEMM_BLOCKS ((NNODE + 63) / 64)  // 782

typedef __attribute__((ext_vector_type(8))) short short8v;   // 8 bf16 (4 VGPR)
typedef __attribute__((ext_vector_type(4))) float float4v;   // MFMA acc

__device__ __forceinline__ unsigned short f2bf(float f) {
    unsigned u = __float_as_uint(f);
    u += 0x7FFFu + ((u >> 16) & 1u);     // RNE
    return (unsigned short)(u >> 16);
}
__device__ __forceinline__ __half2 u_as_h2(unsigned u) {
    return *reinterpret_cast<__half2*>(&u);
}

// ---------------------------------------------------------------------------
// K0: zero the bucket cursors.
// ---------------------------------------------------------------------------
__global__ __launch_bounds__(256)
void zero_kernel(unsigned int* __restrict__ g)
{
    const int i = blockIdx.x * 256 + threadIdx.x;
    if (i < 2 * NBUCK) g[i] = 0u;
}

// ---------------------------------------------------------------------------
// K1: bucket-append scatter, 16384-edge chunks (32/thread, unrolled ->
// registers). packed[fb*CAP+pos] = { col | (row&255)<<16 , f16(val) }.
// ---------------------------------------------------------------------------
__global__ __launch_bounds__(512)
void scatter_kernel(const int* __restrict__ row_low, const int* __restrict__ col_low,
                    const float* __restrict__ val_low,
                    const int* __restrict__ row_high, const int* __restrict__ col_high,
                    const float* __restrict__ val_high,
                    unsigned int* __restrict__ gcursor, uint2* __restrict__ packed)
{
    __shared__ unsigned int hist_s[2 * NBUCK];
    __shared__ unsigned int base_s[2 * NBUCK];
    const int t = threadIdx.x;
    const int ebase = blockIdx.x * 16384;

    for (int i = t; i < 2 * NBUCK; i += 512) hist_s[i] = 0u;
    __syncthreads();

    int rows[32]; unsigned int rank[32];
#pragma unroll
    for (int j = 0; j < 32; ++j) {
        const int e = ebase + j * 512 + t;
        rows[j] = 0; rank[j] = 0u;
        if (e < 2 * NEDGE) {
            const int r = (e < NEDGE) ? row_low[e] : row_high[e - NEDGE];
            const int fb = ((e < NEDGE) ? 0 : NBUCK) + (r >> 8);
            rows[j] = r;
            rank[j] = atomicAdd(&hist_s[fb], 1u);
        }
    }
    __syncthreads();
    for (int i = t; i < 2 * NBUCK; i += 512) {
        const unsigned int c = hist_s[i];
        base_s[i] = c ? atomicAdd(&gcursor[i], c) : 0u;
    }
    __syncthreads();
#pragma unroll
    for (int j = 0; j < 32; ++j) {
        const int e = ebase + j * 512 + t;
        if (e < 2 * NEDGE) {
            const int g = (e >= NEDGE);
            const int ee = e - g * NEDGE;
            const int r = rows[j];
            const int c = g ? col_high[ee] : col_low[ee];
            const float v = g ? val_high[ee] : val_low[ee];
            const int fb = g * NBUCK + (r >> 8);
            const unsigned int pos = base_s[fb] + rank[j];
            if (pos < CAP) {
                uint2 pk;
                pk.x = (unsigned int)c | ((unsigned int)(r & 255) << 16);
                pk.y = (unsigned)__half_as_ushort(__float2half(v));
                packed[(size_t)fb * CAP + pos] = pk;
            }
        }
    }
}

// ---------------------------------------------------------------------------
// K2: fused [sort | gemm] by blockIdx split.
// Sort: row-only counting sort (256 rows, 4-wave scan), compact 4B records
// padded to mult-of-8 per node. rs = start slot; rc = padded_count/4 (even).
// ---------------------------------------------------------------------------
__global__ __launch_bounds__(256)
void sort_gemm_kernel(const uint2* __restrict__ packed,
                      unsigned int* __restrict__ rec4,
                      const unsigned int* __restrict__ gcursor,
                      int* __restrict__ rs, int* __restrict__ rc,
                      const float* __restrict__ x,
                      const float* __restrict__ Wl, const float* __restrict__ Wh,
                      const float* __restrict__ Wm,
                      unsigned short* __restrict__ hl16,
                      unsigned short* __restrict__ hh16,
                      unsigned short* __restrict__ hm16)
{
    __shared__ char smem[30720];   // sort ~30.6KB | gemm 27.65KB
    const int t = threadIdx.x;

    if (blockIdx.x < SORT_BLOCKS) {
        // ------------------------------ sort -------------------------------
        unsigned int*   rec_s = (unsigned int*)smem;               // CAP*4 = 22016
        unsigned char*  row_s = (unsigned char*)(rec_s + CAP);     // CAP   = 5504
        unsigned int*   hist  = (unsigned int*)(row_s + CAP);      // 256*4
        unsigned int*   offs  = hist + 256;                        // 256*4
        unsigned int*   cur   = offs + 256;                        // 256*4
        unsigned int*   wsum4 = cur + 256;                         // 4*4

        const int fb = blockIdx.x;
        const uint2* __restrict__ seg = packed + (size_t)fb * CAP;
        unsigned int* __restrict__ rout = rec4 + (size_t)fb * CAP;
        int cnt = (int)gcursor[fb];
        if (cnt > CAP) cnt = CAP;

        hist[t] = 0u; cur[t] = 0u;
        __syncthreads();

        for (int i = t; i < cnt; i += 256) {
            const uint2 p = seg[i];
            const unsigned r = (p.x >> 16) & 255u;
            rec_s[i] = (p.x & 0xFFFFu) | (p.y << 16);
            row_s[i] = (unsigned char)r;
            atomicAdd(&hist[r], 1u);
        }
        __syncthreads();

        const unsigned pv = (hist[t] + 7u) & ~7u;
        unsigned xinc = pv;
#pragma unroll
        for (int d = 1; d < 64; d <<= 1) {
            unsigned y = __shfl_up(xinc, d, 64);
            if ((t & 63) >= d) xinc += y;
        }
        if ((t & 63) == 63) wsum4[t >> 6] = xinc;
        __syncthreads();
        {
            const int w = t >> 6;
            unsigned add = 0;
            if (w > 0) add += wsum4[0];
            if (w > 1) add += wsum4[1];
            if (w > 2) add += wsum4[2];
            offs[t] = add + xinc - pv;
        }
        __syncthreads();

        for (int i = t; i < cnt; i += 256) {
            const unsigned r = row_s[i];
            const unsigned pos = offs[r] + atomicAdd(&cur[r], 1u);
            if (pos < CAP) rout[pos] = rec_s[i];
        }
        {   // pad records {col=0,val=0}
            const unsigned b = offs[t] + hist[t];
            const unsigned e = offs[t] + ((hist[t] + 7u) & ~7u);
            for (unsigned u = b; u < e && u < CAP; ++u) rout[u] = 0u;
        }

        {
            const int g = (fb >= NBUCK);
            const int node = ((fb - g * NBUCK) << 8) + t;
            if (node < NNODE) {
                const unsigned P = (hist[t] + 7u) & ~7u;
                const int avail = CAP - (int)offs[t];
                int nq = (int)(P >> 2);                          // 4-edge quads, even
                int nqa = avail > 0 ? ((avail >> 2) & ~1) : 0;
                if (nq > nqa) nq = nqa;
                rs[g * NNODE + node] = fb * CAP + (int)offs[t];
                rc[g * NNODE + node] = nq;
            }
        }
    } else {
        // ------------------------------ gemm -------------------------------
        typedef unsigned short wt_t[64][72];
        wt_t* wt = (wt_t*)smem;            // [3][64][72] bf16, 27648B

#pragma unroll 1
        for (int m = 0; m < 3; ++m) {
            const float* __restrict__ W = (m == 0) ? Wl : (m == 1) ? Wh : Wm;
            for (int i = t; i < 4096; i += 256) {
                const int k = i >> 6, c = i & 63;
                wt[m][c][k] = f2bf(W[i]);
            }
        }
        __syncthreads();

        const int wid = t >> 6, lane = t & 63;
        const int node0 = (blockIdx.x - SORT_BLOCKS) * 64 + wid * 16;
        if (node0 >= NNODE) return;
        const int arow = lane & 15;
        const int hi = lane >> 4;

        const float* __restrict__ xr = x + (size_t)(node0 + arow) * 64 + hi * 8;
        const float4 pa0 = *(const float4*)(xr + 0);
        const float4 pa1 = *(const float4*)(xr + 4);
        const float4 pb0 = *(const float4*)(xr + 32);
        const float4 pb1 = *(const float4*)(xr + 36);
        short8v a0, a1;
        a0[0] = (short)f2bf(pa0.x); a0[1] = (short)f2bf(pa0.y);
        a0[2] = (short)f2bf(pa0.z); a0[3] = (short)f2bf(pa0.w);
        a0[4] = (short)f2bf(pa1.x); a0[5] = (short)f2bf(pa1.y);
        a0[6] = (short)f2bf(pa1.z); a0[7] = (short)f2bf(pa1.w);
        a1[0] = (short)f2bf(pb0.x); a1[1] = (short)f2bf(pb0.y);
        a1[2] = (short)f2bf(pb0.z); a1[3] = (short)f2bf(pb0.w);
        a1[4] = (short)f2bf(pb1.x); a1[5] = (short)f2bf(pb1.y);
        a1[6] = (short)f2bf(pb1.z); a1[7] = (short)f2bf(pb1.w);

#pragma unroll 1
        for (int m = 0; m < 3; ++m) {
            unsigned short* __restrict__ H = (m == 0) ? hl16 : (m == 1) ? hh16 : hm16;
            float4v acc0 = {0.f, 0.f, 0.f, 0.f}, acc1 = {0.f, 0.f, 0.f, 0.f};
            float4v acc2 = {0.f, 0.f, 0.f, 0.f}, acc3 = {0.f, 0.f, 0.f, 0.f};

#define DO_CT(CT, ACC)                                                          \
            {                                                                   \
                const short8v b0 = *(const short8v*)&wt[m][CT * 16 + arow][hi * 8]; \
                const short8v b1 = *(const short8v*)&wt[m][CT * 16 + arow][32 + hi * 8]; \
                ACC = __builtin_amdgcn_mfma_f32_16x16x32_bf16(a0, b0, ACC, 0, 0, 0); \
                ACC = __builtin_amdgcn_mfma_f32_16x16x32_bf16(a1, b1, ACC, 0, 0, 0); \
            }
            DO_CT(0, acc0) DO_CT(1, acc1) DO_CT(2, acc2) DO_CT(3, acc3)
#undef DO_CT

            const bool rl = (m == 2);
#define ST_CT(CT, ACC)                                                          \
            {                                                                   \
                _Pragma("unroll")                                               \
                for (int r = 0; r < 4; ++r) {                                   \
                    float v = ACC[r];                                           \
                    if (rl) v = fmaxf(v, 0.f);                                  \
                    H[(size_t)(node0 + hi * 4 + r) * 64 + CT * 16 + arow] =     \
                        __half_as_ushort(__float2half(v));                      \
                }                                                               \
            }
            ST_CT(0, acc0) ST_CT(1, acc1) ST_CT(2, acc2) ST_CT(3, acc3)
#undef ST_CT
        }
    }
}

// ---------------------------------------------------------------------------
// K3: wave-per-node quad-gather spmm + fused finalize.
// 16 lanes/edge, 4B records, packed f16 math. 4-quad main loop (8 records +
// 8 gathers in flight), 2-quad tail (rc even). rc in 4-edge quads.
// ---------------------------------------------------------------------------
#define GATH(hg_, rr_) (*(const uint2*)((const char*)(hg_) + (size_t)((((rr_) & 0xFFFFu) << 7) + fb2)))
#define DSWAP(rr_) (((rr_) & 0xFFFF0000u) | ((rr_) >> 16))

__global__ __launch_bounds__(256, 4)
void spmm_finalize_kernel(const unsigned int* __restrict__ rec4,
                          const int* __restrict__ rs, const int* __restrict__ rc,
                          const unsigned short* __restrict__ hl16,
                          const unsigned short* __restrict__ hh16,
                          const unsigned short* __restrict__ hm16,
                          const float* __restrict__ aL, const float* __restrict__ aH,
                          const float* __restrict__ aM, const float* __restrict__ att3,
                          float* __restrict__ out)
{
    const int wid = threadIdx.x >> 6;
    const int lane = threadIdx.x & 63;
    const int sub = lane >> 4;
    const int f4 = (lane & 15) << 2;
    const unsigned fb2 = (unsigned)(f4 * 2);   // byte offset into f16 row
    const int node = blockIdx.x * 4 + wid;
    if (node >= NNODE) return;

    const int sL = __builtin_amdgcn_readfirstlane(rs[node]);
    const int nqL = __builtin_amdgcn_readfirstlane(rc[node]);
    const int sH = __builtin_amdgcn_readfirstlane(rs[NNODE + node]);
    const int nqH = __builtin_amdgcn_readfirstlane(rc[NNODE + node]);
    const unsigned int* __restrict__ segL = rec4 + sL + sub;   // per-lane base
    const unsigned int* __restrict__ segH = rec4 + sH + sub;
    const int nqm = (nqL > nqH) ? nqL : nqH;

    const __half2 hz2 = u_as_h2(0u);
    __half2 aL0a = hz2, aL1a = hz2, aL0b = hz2, aL1b = hz2;
    __half2 aH0a = hz2, aH1a = hz2, aH0b = hz2, aH1b = hz2;

    int q = 0;
#pragma unroll 1
    for (; q + 4 <= nqm; q += 4) {
        const unsigned rL0 = segL[q * 4],      rL1 = segL[q * 4 + 4];
        const unsigned rL2 = segL[q * 4 + 8],  rL3 = segL[q * 4 + 12];
        const unsigned rH0 = segH[q * 4],      rH1 = segH[q * 4 + 4];
        const unsigned rH2 = segH[q * 4 + 8],  rH3 = segH[q * 4 + 12];
        const uint2 uL0 = GATH(hl16, rL0), uL1 = GATH(hl16, rL1);
        const uint2 uL2 = GATH(hl16, rL2), uL3 = GATH(hl16, rL3);
        const uint2 uH0 = GATH(hh16, rH0), uH1 = GATH(hh16, rH1);
        const uint2 uH2 = GATH(hh16, rH2), uH3 = GATH(hh16, rH3);
        __builtin_amdgcn_sched_barrier(0);   // keep all 16 loads issued here
        const __half2 vL0 = u_as_h2((q     < nqL) ? DSWAP(rL0) : 0u);
        const __half2 vL1 = u_as_h2((q + 1 < nqL) ? DSWAP(rL1) : 0u);
        const __half2 vL2 = u_as_h2((q + 2 < nqL) ? DSWAP(rL2) : 0u);
        const __half2 vL3 = u_as_h2((q + 3 < nqL) ? DSWAP(rL3) : 0u);
        const __half2 vH0 = u_as_h2((q     < nqH) ? DSWAP(rH0) : 0u);
        const __half2 vH1 = u_as_h2((q + 1 < nqH) ? DSWAP(rH1) : 0u);
        const __half2 vH2 = u_as_h2((q + 2 < nqH) ? DSWAP(rH2) : 0u);
        const __half2 vH3 = u_as_h2((q + 3 < nqH) ? DSWAP(rH3) : 0u);
        aL0a = __hfma2(u_as_h2(uL0.x), vL0, aL0a);
        aL1a = __hfma2(u_as_h2(uL0.y), vL0, aL1a);
        aL0b = __hfma2(u_as_h2(uL1.x), vL1, aL0b);
        aL1b = __hfma2(u_as_h2(uL1.y), vL1, aL1b);
        aL0a = __hfma2(u_as_h2(uL2.x), vL2, aL0a);
        aL1a = __hfma2(u_as_h2(uL2.y), vL2, aL1a);
        aL0b = __hfma2(u_as_h2(uL3.x), vL3, aL0b);
        aL1b = __hfma2(u_as_h2(uL3.y), vL3, aL1b);
        aH0a = __hfma2(u_as_h2(uH0.x), vH0, aH0a);
        aH1a = __hfma2(u_as_h2(uH0.y), vH0, aH1a);
        aH0b = __hfma2(u_as_h2(uH1.x), vH1, aH0b);
        aH1b = __hfma2(u_as_h2(uH1.y), vH1, aH1b);
        aH0a = __hfma2(u_as_h2(uH2.x), vH2, aH0a);
        aH1a = __hfma2(u_as_h2(uH2.y), vH2, aH1a);
        aH0b = __hfma2(u_as_h2(uH3.x), vH3, aH0b);
        aH1b = __hfma2(u_as_h2(uH3.y), vH3, aH1b);
    }
#pragma unroll 1
    for (; q + 2 <= nqm; q += 2) {
        const unsigned rL0 = segL[q * 4], rL1 = segL[q * 4 + 4];
        const unsigned rH0 = segH[q * 4], rH1 = segH[q * 4 + 4];
        const uint2 uL0 = GATH(hl16, rL0), uL1 = GATH(hl16, rL1);
        const uint2 uH0 = GATH(hh16, rH0), uH1 = GATH(hh16, rH1);
        __builtin_amdgcn_sched_barrier(0);
        const __half2 vL0 = u_as_h2((q     < nqL) ? DSWAP(rL0) : 0u);
        const __half2 vL1 = u_as_h2((q + 1 < nqL) ? DSWAP(rL1) : 0u);
        const __half2 vH0 = u_as_h2((q     < nqH) ? DSWAP(rH0) : 0u);
        const __half2 vH1 = u_as_h2((q + 1 < nqH) ? DSWAP(rH1) : 0u);
        aL0a = __hfma2(u_as_h2(uL0.x), vL0, aL0a);
        aL1a = __hfma2(u_as_h2(uL0.y), vL0, aL1a);
        aL0b = __hfma2(u_as_h2(uL1.x), vL1, aL0b);
        aL1b = __hfma2(u_as_h2(uL1.y), vL1, aL1b);
        aH0a = __hfma2(u_as_h2(uH0.x), vH0, aH0a);
        aH1a = __hfma2(u_as_h2(uH0.y), vH0, aH1a);
        aH0b = __hfma2(u_as_h2(uH1.x), vH1, aH0b);
        aH1b = __hfma2(u_as_h2(uH1.y), vH1, aH1b);
    }

    float lx = __low2float(aL0a) + __low2float(aL0b);
    float ly = __high2float(aL0a) + __high2float(aL0b);
    float lz = __low2float(aL1a) + __low2float(aL1b);
    float lw = __high2float(aL1a) + __high2float(aL1b);
    float hx = __low2float(aH0a) + __low2float(aH0b);
    float hy = __high2float(aH0a) + __high2float(aH0b);
    float hz = __low2float(aH1a) + __low2float(aH1b);
    float hw = __high2float(aH1a) + __high2float(aH1b);

    lx += __shfl_xor(lx, 16, 64); ly += __shfl_xor(ly, 16, 64);
    lz += __shfl_xor(lz, 16, 64); lw += __shfl_xor(lw, 16, 64);
    hx += __shfl_xor(hx, 16, 64); hy += __shfl_xor(hy, 16, 64);
    hz += __shfl_xor(hz, 16, 64); hw += __shfl_xor(hw, 16, 64);
    lx += __shfl_xor(lx, 32, 64); ly += __shfl_xor(ly, 32, 64);
    lz += __shfl_xor(lz, 32, 64); lw += __shfl_xor(lw, 32, 64);
    hx += __shfl_xor(hx, 32, 64); hy += __shfl_xor(hy, 32, 64);
    hz += __shfl_xor(hz, 32, 64); hw += __shfl_xor(hw, 32, 64);

    const float olx = fmaxf(lx, 0.f), oly = fmaxf(ly, 0.f);
    const float olz = fmaxf(lz, 0.f), olw = fmaxf(lw, 0.f);
    const float ohx = fmaxf(hx, 0.f), ohy = fmaxf(hy, 0.f);
    const float ohz = fmaxf(hz, 0.f), ohw = fmaxf(hw, 0.f);

    const uint2 om2 = *(const uint2*)&hm16[(size_t)node * 64 + f4];
    const float omx = __low2float(u_as_h2(om2.x));
    const float omy = __high2float(u_as_h2(om2.x));
    const float omz = __low2float(u_as_h2(om2.y));
    const float omw = __high2float(u_as_h2(om2.y));

    const float4 aL4 = *(const float4*)&aL[f4];
    const float4 aH4 = *(const float4*)&aH[f4];
    const float4 aM4 = *(const float4*)&aM[f4];

    float f0 = olx * aL4.x + oly * aL4.y + olz * aL4.z + olw * aL4.w;
    float f1 = ohx * aH4.x + ohy * aH4.y + ohz * aH4.z + ohw * aH4.w;
    float f2 = omx * aM4.x + omy * aM4.y + omz * aM4.z + omw * aM4.w;
#pragma unroll
    for (int msk = 1; msk < 16; msk <<= 1) {
        f0 += __shfl_xor(f0, msk, 64);
        f1 += __shfl_xor(f1, msk, 64);
        f2 += __shfl_xor(f2, msk, 64);
    }
    const float s0 = 1.f / (1.f + __expf(-f0));
    const float s1 = 1.f / (1.f + __expf(-f1));
    const float s2 = 1.f / (1.f + __expf(-f2));
    const float invT = 1.f / 3.f;
    const float l0g = (s0 * att3[0] + s1 * att3[3] + s2 * att3[6]) * invT;
    const float l1g = (s0 * att3[1] + s1 * att3[4] + s2 * att3[7]) * invT;
    const float l2g = (s0 * att3[2] + s1 * att3[5] + s2 * att3[8]) * invT;
    const float mx = fmaxf(l0g, fmaxf(l1g, l2g));
    const float e0 = __expf(l0g - mx);
    const float e1 = __expf(l1g - mx);
    const float e2 = __expf(l2g - mx);
    const float inv = 1.f / (e0 + e1 + e2);
    const float wl = 3.f * inv * e0, wh = 3.f * inv * e1, wm = 3.f * inv * e2;

    if (lane < 16) {
        float4 o;
        o.x = wl * olx + wh * ohx + wm * omx;
        o.y = wl * oly + wh * ohy + wm * omy;
        o.z = wl * olz + wh * ohz + wm * omz;
        o.w = wl * olw + wh * ohw + wm * omw;
        *(float4*)&out[(size_t)node * 64 + f4] = o;
    }
}

extern "C" void kernel_launch(void* const* d_in, const int* in_sizes, int n_in,
                              void* d_out, int out_size, void* d_ws, size_t ws_size,
                              hipStream_t stream)
{
    const float* x        = (const float*)d_in[0];
    const int*   row_low  = (const int*)  d_in[1];
    const int*   col_low  = (const int*)  d_in[2];
    const float* val_low  = (const float*)d_in[3];
    const int*   row_high = (const int*)  d_in[4];
    const int*   col_high = (const int*)  d_in[5];
    const float* val_high = (const float*)d_in[6];
    const float* W_low    = (const float*)d_in[7];
    const float* W_high   = (const float*)d_in[8];
    const float* W_mlp    = (const float*)d_in[9];
    const float* a_low    = (const float*)d_in[10];
    const float* a_high   = (const float*)d_in[11];
    const float* a_mlp    = (const float*)d_in[12];
    const float* att3     = (const float*)d_in[13];
    float* out = (float*)d_out;

    const size_t NM = (size_t)NNODE * 64;
    const size_t NSLOT = (size_t)2 * NBUCK * CAP;

    unsigned short* hl16    = (unsigned short*)d_ws;          // N*64 f16
    unsigned short* hh16    = hl16 + NM;                      // N*64 f16
    unsigned short* hm16    = hh16 + NM;                      // N*64 f16
    uint2*          packed  = (uint2*)(hm16 + NM);            // NSLOT uint2
    unsigned int*   rec4    = (unsigned int*)(packed + NSLOT);// NSLOT u32
    unsigned int*   gcursor = rec4 + NSLOT;                   // 2*NBUCK
    int*            rs      = (int*)(gcursor + 2 * NBUCK);    // 2*N
    int*            rc      = rs + 2 * NNODE;                 // 2*N

    zero_kernel<<<(2 * NBUCK + 255) / 256, 256, 0, stream>>>(gcursor);

    scatter_kernel<<<(2 * NEDGE + 16383) / 16384, 512, 0, stream>>>(
        row_low, col_low, val_low, row_high, col_high, val_high, gcursor, packed);

    sort_gemm_kernel<<<SORT_BLOCKS + GEMM_BLOCKS, 256, 0, stream>>>(
        packed, rec4, gcursor, rs, rc,
        x, W_low, W_high, W_mlp, hl16, hh16, hm16);

    spmm_finalize_kernel<<<(NNODE + 3) / 4, 256, 0, stream>>>(
        rec4, rs, rc, hl16, hh16, hm16, a_low, a_high, a_mlp, att3, out);
}

// Round 18
// 82.241 us; speedup vs baseline: 1.1065x; 1.1065x over previous
//
#include <hip/hip_runtime.h>
#include <hip/hip_fp16.h>

// ACM-GCN graph conv, R18 = R15 geometry + R17 4-quad spmm.
// R17 post-mortem: 16384-edge chunks -> 98-block grid -> 7% occupancy ->
// scatter latency-starved at 0.5TB/s despite only 23MB traffic. Revert to
// 128-node buckets + 8192-edge chunks (196 blocks, the 85.6us config);
// keep the 4-quad spmm inner loop (16 loads in flight).

#define NNODE 50000
#define NEDGE 800000
#define NBUCK 391              // 128-node buckets per graph (49999>>7 = 390)
#define CAP   2880             // slots/bucket: padded mean ~2496 + 8.5 sigma, %8==0
#define SORT_BLOCKS (2 * NBUCK)          // 782
#define GEMM_BLOCKS ((NNODE + 63) / 64)  // 782

typedef __attribute__((ext_vector_type(8))) short short8v;   // 8 bf16 (4 VGPR)
typedef __attribute__((ext_vector_type(4))) float float4v;   // MFMA acc

__device__ __forceinline__ unsigned short f2bf(float f) {
    unsigned u = __float_as_uint(f);
    u += 0x7FFFu + ((u >> 16) & 1u);     // RNE
    return (unsigned short)(u >> 16);
}
__device__ __forceinline__ __half2 u_as_h2(unsigned u) {
    return *reinterpret_cast<__half2*>(&u);
}

// ---------------------------------------------------------------------------
// K0: zero the bucket cursors.
// ---------------------------------------------------------------------------
__global__ __launch_bounds__(256)
void zero_kernel(unsigned int* __restrict__ g)
{
    const int i = blockIdx.x * 256 + threadIdx.x;
    if (i < 2 * NBUCK) g[i] = 0u;
}

// ---------------------------------------------------------------------------
// K1: bucket-append scatter, 8192-edge chunks (16/thread), 196 blocks.
// packed[fb*CAP+pos] = { col | (row&127)<<16 , f16(val) in low 16 }.
// ---------------------------------------------------------------------------
__global__ __launch_bounds__(512)
void scatter_kernel(const int* __restrict__ row_low, const int* __restrict__ col_low,
                    const float* __restrict__ val_low,
                    const int* __restrict__ row_high, const int* __restrict__ col_high,
                    const float* __restrict__ val_high,
                    unsigned int* __restrict__ gcursor, uint2* __restrict__ packed)
{
    __shared__ unsigned int hist_s[2 * NBUCK];
    __shared__ unsigned int base_s[2 * NBUCK];
    const int t = threadIdx.x;
    const int ebase = blockIdx.x * 8192;

    for (int i = t; i < 2 * NBUCK; i += 512) hist_s[i] = 0u;
    __syncthreads();

    int rows[16]; unsigned int rank[16];
#pragma unroll
    for (int j = 0; j < 16; ++j) {
        const int e = ebase + j * 512 + t;
        rows[j] = 0; rank[j] = 0u;
        if (e < 2 * NEDGE) {
            const int r = (e < NEDGE) ? row_low[e] : row_high[e - NEDGE];
            const int fb = ((e < NEDGE) ? 0 : NBUCK) + (r >> 7);
            rows[j] = r;
            rank[j] = atomicAdd(&hist_s[fb], 1u);
        }
    }
    __syncthreads();
    for (int i = t; i < 2 * NBUCK; i += 512) {
        const unsigned int c = hist_s[i];
        base_s[i] = c ? atomicAdd(&gcursor[i], c) : 0u;
    }
    __syncthreads();
#pragma unroll
    for (int j = 0; j < 16; ++j) {
        const int e = ebase + j * 512 + t;
        if (e < 2 * NEDGE) {
            const int g = (e >= NEDGE);
            const int ee = e - g * NEDGE;
            const int r = rows[j];
            const int c = g ? col_high[ee] : col_low[ee];
            const float v = g ? val_high[ee] : val_low[ee];
            const int fb = g * NBUCK + (r >> 7);
            const unsigned int pos = base_s[fb] + rank[j];
            if (pos < CAP) {
                uint2 pk;
                pk.x = (unsigned int)c | ((unsigned int)(r & 127) << 16);
                pk.y = (unsigned)__half_as_ushort(__float2half(v));
                packed[(size_t)fb * CAP + pos] = pk;
            }
        }
    }
}

// ---------------------------------------------------------------------------
// K2: fused [sort | gemm] by blockIdx split (R15 structure).
// Sort: row-only counting sort (128 rows, 2-wave scan), compact 4B records
// padded to mult-of-8 per node. rs = start slot; rc = padded_count/4 (even).
// ---------------------------------------------------------------------------
__global__ __launch_bounds__(256)
void sort_gemm_kernel(const uint2* __restrict__ packed,
                      unsigned int* __restrict__ rec4,
                      const unsigned int* __restrict__ gcursor,
                      int* __restrict__ rs, int* __restrict__ rc,
                      const float* __restrict__ x,
                      const float* __restrict__ Wl, const float* __restrict__ Wh,
                      const float* __restrict__ Wm,
                      unsigned short* __restrict__ hl16,
                      unsigned short* __restrict__ hh16,
                      unsigned short* __restrict__ hm16)
{
    __shared__ char smem[27648];   // gemm wt 27648B | sort ~15.9KB
    const int t = threadIdx.x;

    if (blockIdx.x < SORT_BLOCKS) {
        // ------------------------------ sort -------------------------------
        unsigned int*  rec_s = (unsigned int*)smem;            // CAP*4 = 11520
        unsigned char* row_s = (unsigned char*)(rec_s + CAP);  // CAP
        unsigned int*  hist  = (unsigned int*)(row_s + CAP);   // 128
        unsigned int*  offs  = hist + 128;
        unsigned int*  cur   = offs + 128;
        unsigned int*  wsum2 = cur + 128;

        const int fb = blockIdx.x;
        const uint2* __restrict__ seg = packed + (size_t)fb * CAP;
        unsigned int* __restrict__ rout = rec4 + (size_t)fb * CAP;
        int cnt = (int)gcursor[fb];
        if (cnt > CAP) cnt = CAP;

        if (t < 128) { hist[t] = 0u; cur[t] = 0u; }
        __syncthreads();

        for (int i = t; i < cnt; i += 256) {
            const uint2 p = seg[i];
            const unsigned r = (p.x >> 16) & 127u;
            rec_s[i] = (p.x & 0xFFFFu) | (p.y << 16);
            row_s[i] = (unsigned char)r;
            atomicAdd(&hist[r], 1u);
        }
        __syncthreads();

        unsigned pv = 0, xinc = 0;
        if (t < 128) {   // padded counts, 2-wave scan
            pv = (hist[t] + 7u) & ~7u;
            xinc = pv;
#pragma unroll
            for (int d = 1; d < 64; d <<= 1) {
                unsigned y = __shfl_up(xinc, d, 64);
                if ((t & 63) >= d) xinc += y;
            }
            if ((t & 63) == 63) wsum2[t >> 6] = xinc;
        }
        __syncthreads();
        if (t < 128) {
            const unsigned add = (t >= 64) ? wsum2[0] : 0u;
            offs[t] = add + xinc - pv;
        }
        __syncthreads();

        for (int i = t; i < cnt; i += 256) {
            const unsigned r = row_s[i];
            const unsigned pos = offs[r] + atomicAdd(&cur[r], 1u);
            if (pos < CAP) rout[pos] = rec_s[i];
        }
        if (t < 128) {   // pad records {col=0,val=0}
            const unsigned b = offs[t] + hist[t];
            const unsigned e = offs[t] + ((hist[t] + 7u) & ~7u);
            for (unsigned u = b; u < e && u < CAP; ++u) rout[u] = 0u;
        }

        if (t < 128) {
            const int g = (fb >= NBUCK);
            const int node = ((fb - g * NBUCK) << 7) + t;
            if (node < NNODE) {
                const unsigned P = (hist[t] + 7u) & ~7u;
                const int avail = CAP - (int)offs[t];
                int nq = (int)(P >> 2);                          // 4-edge quads, even
                int nqa = avail > 0 ? ((avail >> 2) & ~1) : 0;
                if (nq > nqa) nq = nqa;
                rs[g * NNODE + node] = fb * CAP + (int)offs[t];
                rc[g * NNODE + node] = nq;
            }
        }
    } else {
        // ------------------------------ gemm -------------------------------
        typedef unsigned short wt_t[64][72];
        wt_t* wt = (wt_t*)smem;            // [3][64][72] bf16, 27648B

#pragma unroll 1
        for (int m = 0; m < 3; ++m) {
            const float* __restrict__ W = (m == 0) ? Wl : (m == 1) ? Wh : Wm;
            for (int i = t; i < 4096; i += 256) {
                const int k = i >> 6, c = i & 63;
                wt[m][c][k] = f2bf(W[i]);
            }
        }
        __syncthreads();

        const int wid = t >> 6, lane = t & 63;
        const int node0 = (blockIdx.x - SORT_BLOCKS) * 64 + wid * 16;
        if (node0 >= NNODE) return;
        const int arow = lane & 15;
        const int hi = lane >> 4;

        const float* __restrict__ xr = x + (size_t)(node0 + arow) * 64 + hi * 8;
        const float4 pa0 = *(const float4*)(xr + 0);
        const float4 pa1 = *(const float4*)(xr + 4);
        const float4 pb0 = *(const float4*)(xr + 32);
        const float4 pb1 = *(const float4*)(xr + 36);
        short8v a0, a1;
        a0[0] = (short)f2bf(pa0.x); a0[1] = (short)f2bf(pa0.y);
        a0[2] = (short)f2bf(pa0.z); a0[3] = (short)f2bf(pa0.w);
        a0[4] = (short)f2bf(pa1.x); a0[5] = (short)f2bf(pa1.y);
        a0[6] = (short)f2bf(pa1.z); a0[7] = (short)f2bf(pa1.w);
        a1[0] = (short)f2bf(pb0.x); a1[1] = (short)f2bf(pb0.y);
        a1[2] = (short)f2bf(pb0.z); a1[3] = (short)f2bf(pb0.w);
        a1[4] = (short)f2bf(pb1.x); a1[5] = (short)f2bf(pb1.y);
        a1[6] = (short)f2bf(pb1.z); a1[7] = (short)f2bf(pb1.w);

#pragma unroll 1
        for (int m = 0; m < 3; ++m) {
            unsigned short* __restrict__ H = (m == 0) ? hl16 : (m == 1) ? hh16 : hm16;
            float4v acc0 = {0.f, 0.f, 0.f, 0.f}, acc1 = {0.f, 0.f, 0.f, 0.f};
            float4v acc2 = {0.f, 0.f, 0.f, 0.f}, acc3 = {0.f, 0.f, 0.f, 0.f};

#define DO_CT(CT, ACC)                                                          \
            {                                                                   \
                const short8v b0 = *(const short8v*)&wt[m][CT * 16 + arow][hi * 8]; \
                const short8v b1 = *(const short8v*)&wt[m][CT * 16 + arow][32 + hi * 8]; \
                ACC = __builtin_amdgcn_mfma_f32_16x16x32_bf16(a0, b0, ACC, 0, 0, 0); \
                ACC = __builtin_amdgcn_mfma_f32_16x16x32_bf16(a1, b1, ACC, 0, 0, 0); \
            }
            DO_CT(0, acc0) DO_CT(1, acc1) DO_CT(2, acc2) DO_CT(3, acc3)
#undef DO_CT

            const bool rl = (m == 2);
#define ST_CT(CT, ACC)                                                          \
            {                                                                   \
                _Pragma("unroll")                                               \
                for (int r = 0; r < 4; ++r) {                                   \
                    float v = ACC[r];                                           \
                    if (rl) v = fmaxf(v, 0.f);                                  \
                    H[(size_t)(node0 + hi * 4 + r) * 64 + CT * 16 + arow] =     \
                        __half_as_ushort(__float2half(v));                      \
                }                                                               \
            }
            ST_CT(0, acc0) ST_CT(1, acc1) ST_CT(2, acc2) ST_CT(3, acc3)
#undef ST_CT
        }
    }
}

// ---------------------------------------------------------------------------
// K3: wave-per-node quad-gather spmm + fused finalize.
// 16 lanes/edge, 4B records, packed f16 math. 4-quad main loop (8 records +
// 8 gathers in flight), 2-quad tail (rc even). rc in 4-edge quads.
// ---------------------------------------------------------------------------
#define GATH(hg_, rr_) (*(const uint2*)((const char*)(hg_) + (size_t)((((rr_) & 0xFFFFu) << 7) + fb2)))
#define DSWAP(rr_) (((rr_) & 0xFFFF0000u) | ((rr_) >> 16))

__global__ __launch_bounds__(256, 4)
void spmm_finalize_kernel(const unsigned int* __restrict__ rec4,
                          const int* __restrict__ rs, const int* __restrict__ rc,
                          const unsigned short* __restrict__ hl16,
                          const unsigned short* __restrict__ hh16,
                          const unsigned short* __restrict__ hm16,
                          const float* __restrict__ aL, const float* __restrict__ aH,
                          const float* __restrict__ aM, const float* __restrict__ att3,
                          float* __restrict__ out)
{
    const int wid = threadIdx.x >> 6;
    const int lane = threadIdx.x & 63;
    const int sub = lane >> 4;
    const int f4 = (lane & 15) << 2;
    const unsigned fb2 = (unsigned)(f4 * 2);   // byte offset into f16 row
    const int node = blockIdx.x * 4 + wid;
    if (node >= NNODE) return;

    const int sL = __builtin_amdgcn_readfirstlane(rs[node]);
    const int nqL = __builtin_amdgcn_readfirstlane(rc[node]);
    const int sH = __builtin_amdgcn_readfirstlane(rs[NNODE + node]);
    const int nqH = __builtin_amdgcn_readfirstlane(rc[NNODE + node]);
    const unsigned int* __restrict__ segL = rec4 + sL + sub;   // per-lane base
    const unsigned int* __restrict__ segH = rec4 + sH + sub;
    const int nqm = (nqL > nqH) ? nqL : nqH;

    const __half2 hz2 = u_as_h2(0u);
    __half2 aL0a = hz2, aL1a = hz2, aL0b = hz2, aL1b = hz2;
    __half2 aH0a = hz2, aH1a = hz2, aH0b = hz2, aH1b = hz2;

    int q = 0;
#pragma unroll 1
    for (; q + 4 <= nqm; q += 4) {
        const unsigned rL0 = segL[q * 4],      rL1 = segL[q * 4 + 4];
        const unsigned rL2 = segL[q * 4 + 8],  rL3 = segL[q * 4 + 12];
        const unsigned rH0 = segH[q * 4],      rH1 = segH[q * 4 + 4];
        const unsigned rH2 = segH[q * 4 + 8],  rH3 = segH[q * 4 + 12];
        const uint2 uL0 = GATH(hl16, rL0), uL1 = GATH(hl16, rL1);
        const uint2 uL2 = GATH(hl16, rL2), uL3 = GATH(hl16, rL3);
        const uint2 uH0 = GATH(hh16, rH0), uH1 = GATH(hh16, rH1);
        const uint2 uH2 = GATH(hh16, rH2), uH3 = GATH(hh16, rH3);
        __builtin_amdgcn_sched_barrier(0);   // keep all 16 loads issued here
        const __half2 vL0 = u_as_h2((q     < nqL) ? DSWAP(rL0) : 0u);
        const __half2 vL1 = u_as_h2((q + 1 < nqL) ? DSWAP(rL1) : 0u);
        const __half2 vL2 = u_as_h2((q + 2 < nqL) ? DSWAP(rL2) : 0u);
        const __half2 vL3 = u_as_h2((q + 3 < nqL) ? DSWAP(rL3) : 0u);
        const __half2 vH0 = u_as_h2((q     < nqH) ? DSWAP(rH0) : 0u);
        const __half2 vH1 = u_as_h2((q + 1 < nqH) ? DSWAP(rH1) : 0u);
        const __half2 vH2 = u_as_h2((q + 2 < nqH) ? DSWAP(rH2) : 0u);
        const __half2 vH3 = u_as_h2((q + 3 < nqH) ? DSWAP(rH3) : 0u);
        aL0a = __hfma2(u_as_h2(uL0.x), vL0, aL0a);
        aL1a = __hfma2(u_as_h2(uL0.y), vL0, aL1a);
        aL0b = __hfma2(u_as_h2(uL1.x), vL1, aL0b);
        aL1b = __hfma2(u_as_h2(uL1.y), vL1, aL1b);
        aL0a = __hfma2(u_as_h2(uL2.x), vL2, aL0a);
        aL1a = __hfma2(u_as_h2(uL2.y), vL2, aL1a);
        aL0b = __hfma2(u_as_h2(uL3.x), vL3, aL0b);
        aL1b = __hfma2(u_as_h2(uL3.y), vL3, aL1b);
        aH0a = __hfma2(u_as_h2(uH0.x), vH0, aH0a);
        aH1a = __hfma2(u_as_h2(uH0.y), vH0, aH1a);
        aH0b = __hfma2(u_as_h2(uH1.x), vH1, aH0b);
        aH1b = __hfma2(u_as_h2(uH1.y), vH1, aH1b);
        aH0a = __hfma2(u_as_h2(uH2.x), vH2, aH0a);
        aH1a = __hfma2(u_as_h2(uH2.y), vH2, aH1a);
        aH0b = __hfma2(u_as_h2(uH3.x), vH3, aH0b);
        aH1b = __hfma2(u_as_h2(uH3.y), vH3, aH1b);
    }
#pragma unroll 1
    for (; q + 2 <= nqm; q += 2) {
        const unsigned rL0 = segL[q * 4], rL1 = segL[q * 4 + 4];
        const unsigned rH0 = segH[q * 4], rH1 = segH[q * 4 + 4];
        const uint2 uL0 = GATH(hl16, rL0), uL1 = GATH(hl16, rL1);
        const uint2 uH0 = GATH(hh16, rH0), uH1 = GATH(hh16, rH1);
        __builtin_amdgcn_sched_barrier(0);
        const __half2 vL0 = u_as_h2((q     < nqL) ? DSWAP(rL0) : 0u);
        const __half2 vL1 = u_as_h2((q + 1 < nqL) ? DSWAP(rL1) : 0u);
        const __half2 vH0 = u_as_h2((q     < nqH) ? DSWAP(rH0) : 0u);
        const __half2 vH1 = u_as_h2((q + 1 < nqH) ? DSWAP(rH1) : 0u);
        aL0a = __hfma2(u_as_h2(uL0.x), vL0, aL0a);
        aL1a = __hfma2(u_as_h2(uL0.y), vL0, aL1a);
        aL0b = __hfma2(u_as_h2(uL1.x), vL1, aL0b);
        aL1b = __hfma2(u_as_h2(uL1.y), vL1, aL1b);
        aH0a = __hfma2(u_as_h2(uH0.x), vH0, aH0a);
        aH1a = __hfma2(u_as_h2(uH0.y), vH0, aH1a);
        aH0b = __hfma2(u_as_h2(uH1.x), vH1, aH0b);
        aH1b = __hfma2(u_as_h2(uH1.y), vH1, aH1b);
    }

    float lx = __low2float(aL0a) + __low2float(aL0b);
    float ly = __high2float(aL0a) + __high2float(aL0b);
    float lz = __low2float(aL1a) + __low2float(aL1b);
    float lw = __high2float(aL1a) + __high2float(aL1b);
    float hx = __low2float(aH0a) + __low2float(aH0b);
    float hy = __high2float(aH0a) + __high2float(aH0b);
    float hz = __low2float(aH1a) + __low2float(aH1b);
    float hw = __high2float(aH1a) + __high2float(aH1b);

    lx += __shfl_xor(lx, 16, 64); ly += __shfl_xor(ly, 16, 64);
    lz += __shfl_xor(lz, 16, 64); lw += __shfl_xor(lw, 16, 64);
    hx += __shfl_xor(hx, 16, 64); hy += __shfl_xor(hy, 16, 64);
    hz += __shfl_xor(hz, 16, 64); hw += __shfl_xor(hw, 16, 64);
    lx += __shfl_xor(lx, 32, 64); ly += __shfl_xor(ly, 32, 64);
    lz += __shfl_xor(lz, 32, 64); lw += __shfl_xor(lw, 32, 64);
    hx += __shfl_xor(hx, 32, 64); hy += __shfl_xor(hy, 32, 64);
    hz += __shfl_xor(hz, 32, 64); hw += __shfl_xor(hw, 32, 64);

    const float olx = fmaxf(lx, 0.f), oly = fmaxf(ly, 0.f);
    const float olz = fmaxf(lz, 0.f), olw = fmaxf(lw, 0.f);
    const float ohx = fmaxf(hx, 0.f), ohy = fmaxf(hy, 0.f);
    const float ohz = fmaxf(hz, 0.f), ohw = fmaxf(hw, 0.f);

    const uint2 om2 = *(const uint2*)&hm16[(size_t)node * 64 + f4];
    const float omx = __low2float(u_as_h2(om2.x));
    const float omy = __high2float(u_as_h2(om2.x));
    const float omz = __low2float(u_as_h2(om2.y));
    const float omw = __high2float(u_as_h2(om2.y));

    const float4 aL4 = *(const float4*)&aL[f4];
    const float4 aH4 = *(const float4*)&aH[f4];
    const float4 aM4 = *(const float4*)&aM[f4];

    float f0 = olx * aL4.x + oly * aL4.y + olz * aL4.z + olw * aL4.w;
    float f1 = ohx * aH4.x + ohy * aH4.y + ohz * aH4.z + ohw * aH4.w;
    float f2 = omx * aM4.x + omy * aM4.y + omz * aM4.z + omw * aM4.w;
#pragma unroll
    for (int msk = 1; msk < 16; msk <<= 1) {
        f0 += __shfl_xor(f0, msk, 64);
        f1 += __shfl_xor(f1, msk, 64);
        f2 += __shfl_xor(f2, msk, 64);
    }
    const float s0 = 1.f / (1.f + __expf(-f0));
    const float s1 = 1.f / (1.f + __expf(-f1));
    const float s2 = 1.f / (1.f + __expf(-f2));
    const float invT = 1.f / 3.f;
    const float l0g = (s0 * att3[0] + s1 * att3[3] + s2 * att3[6]) * invT;
    const float l1g = (s0 * att3[1] + s1 * att3[4] + s2 * att3[7]) * invT;
    const float l2g = (s0 * att3[2] + s1 * att3[5] + s2 * att3[8]) * invT;
    const float mx = fmaxf(l0g, fmaxf(l1g, l2g));
    const float e0 = __expf(l0g - mx);
    const float e1 = __expf(l1g - mx);
    const float e2 = __expf(l2g - mx);
    const float inv = 1.f / (e0 + e1 + e2);
    const float wl = 3.f * inv * e0, wh = 3.f * inv * e1, wm = 3.f * inv * e2;

    if (lane < 16) {
        float4 o;
        o.x = wl * olx + wh * ohx + wm * omx;
        o.y = wl * oly + wh * ohy + wm * omy;
        o.z = wl * olz + wh * ohz + wm * omz;
        o.w = wl * olw + wh * ohw + wm * omw;
        *(float4*)&out[(size_t)node * 64 + f4] = o;
    }
}

extern "C" void kernel_launch(void* const* d_in, const int* in_sizes, int n_in,
                              void* d_out, int out_size, void* d_ws, size_t ws_size,
                              hipStream_t stream)
{
    const float* x        = (const float*)d_in[0];
    const int*   row_low  = (const int*)  d_in[1];
    const int*   col_low  = (const int*)  d_in[2];
    const float* val_low  = (const float*)d_in[3];
    const int*   row_high = (const int*)  d_in[4];
    const int*   col_high = (const int*)  d_in[5];
    const float* val_high = (const float*)d_in[6];
    const float* W_low    = (const float*)d_in[7];
    const float* W_high   = (const float*)d_in[8];
    const float* W_mlp    = (const float*)d_in[9];
    const float* a_low    = (const float*)d_in[10];
    const float* a_high   = (const float*)d_in[11];
    const float* a_mlp    = (const float*)d_in[12];
    const float* att3     = (const float*)d_in[13];
    float* out = (float*)d_out;

    const size_t NM = (size_t)NNODE * 64;
    const size_t NSLOT = (size_t)2 * NBUCK * CAP;

    unsigned short* hl16    = (unsigned short*)d_ws;          // N*64 f16
    unsigned short* hh16    = hl16 + NM;                      // N*64 f16
    unsigned short* hm16    = hh16 + NM;                      // N*64 f16
    uint2*          packed  = (uint2*)(hm16 + NM);            // NSLOT uint2
    unsigned int*   rec4    = (unsigned int*)(packed + NSLOT);// NSLOT u32
    unsigned int*   gcursor = rec4 + NSLOT;                   // 2*NBUCK
    int*            rs      = (int*)(gcursor + 2 * NBUCK);    // 2*N
    int*            rc      = rs + 2 * NNODE;                 // 2*N

    zero_kernel<<<(2 * NBUCK + 255) / 256, 256, 0, stream>>>(gcursor);

    scatter_kernel<<<(2 * NEDGE + 8191) / 8192, 512, 0, stream>>>(
        row_low, col_low, val_low, row_high, col_high, val_high, gcursor, packed);

    sort_gemm_kernel<<<SORT_BLOCKS + GEMM_BLOCKS, 256, 0, stream>>>(
        packed, rec4, gcursor, rs, rc,
        x, W_low, W_high, W_mlp, hl16, hh16, hm16);

    spmm_finalize_kernel<<<(NNODE + 3) / 4, 256, 0, stream>>>(
        rec4, rs, rc, hl16, hh16, hm16, a_low, a_high, a_mlp, att3, out);
}

// Round 19
// 81.873 us; speedup vs baseline: 1.1115x; 1.0045x over previous
//
#include <hip/hip_runtime.h>
#include <hip/hip_fp16.h>

// ACM-GCN graph conv, R19 = R18 with spmm residency 4->6 waves/SIMD.
// R18 post-mortem: 82.2us; spmm ~36us is latency-bound (issue-bound floor
// ~1.3us; 2 serial round-trips/iter at 4 waves/SIMD residency). R19: single
// change -- __launch_bounds__(256,6) on spmm (~84 VGPR cap, +50% residency).
// Tripwire: spmm WRITE_SIZE > 12.5MB means spill -> revert.

#define NNODE 50000
#define NEDGE 800000
#define NBUCK 391              // 128-node buckets per graph (49999>>7 = 390)
#define CAP   2880             // slots/bucket: padded mean ~2496 + 8.5 sigma, %8==0
#define SORT_BLOCKS (2 * NBUCK)          // 782
#define GEMM_BLOCKS ((NNODE + 63) / 64)  // 782

typedef __attribute__((ext_vector_type(8))) short short8v;   // 8 bf16 (4 VGPR)
typedef __attribute__((ext_vector_type(4))) float float4v;   // MFMA acc

__device__ __forceinline__ unsigned short f2bf(float f) {
    unsigned u = __float_as_uint(f);
    u += 0x7FFFu + ((u >> 16) & 1u);     // RNE
    return (unsigned short)(u >> 16);
}
__device__ __forceinline__ __half2 u_as_h2(unsigned u) {
    return *reinterpret_cast<__half2*>(&u);
}

// ---------------------------------------------------------------------------
// K0: zero the bucket cursors.
// ---------------------------------------------------------------------------
__global__ __launch_bounds__(256)
void zero_kernel(unsigned int* __restrict__ g)
{
    const int i = blockIdx.x * 256 + threadIdx.x;
    if (i < 2 * NBUCK) g[i] = 0u;
}

// ---------------------------------------------------------------------------
// K1: bucket-append scatter, 8192-edge chunks (16/thread), 196 blocks.
// packed[fb*CAP+pos] = { col | (row&127)<<16 , f16(val) in low 16 }.
// ---------------------------------------------------------------------------
__global__ __launch_bounds__(512)
void scatter_kernel(const int* __restrict__ row_low, const int* __restrict__ col_low,
                    const float* __restrict__ val_low,
                    const int* __restrict__ row_high, const int* __restrict__ col_high,
                    const float* __restrict__ val_high,
                    unsigned int* __restrict__ gcursor, uint2* __restrict__ packed)
{
    __shared__ unsigned int hist_s[2 * NBUCK];
    __shared__ unsigned int base_s[2 * NBUCK];
    const int t = threadIdx.x;
    const int ebase = blockIdx.x * 8192;

    for (int i = t; i < 2 * NBUCK; i += 512) hist_s[i] = 0u;
    __syncthreads();

    int rows[16]; unsigned int rank[16];
#pragma unroll
    for (int j = 0; j < 16; ++j) {
        const int e = ebase + j * 512 + t;
        rows[j] = 0; rank[j] = 0u;
        if (e < 2 * NEDGE) {
            const int r = (e < NEDGE) ? row_low[e] : row_high[e - NEDGE];
            const int fb = ((e < NEDGE) ? 0 : NBUCK) + (r >> 7);
            rows[j] = r;
            rank[j] = atomicAdd(&hist_s[fb], 1u);
        }
    }
    __syncthreads();
    for (int i = t; i < 2 * NBUCK; i += 512) {
        const unsigned int c = hist_s[i];
        base_s[i] = c ? atomicAdd(&gcursor[i], c) : 0u;
    }
    __syncthreads();
#pragma unroll
    for (int j = 0; j < 16; ++j) {
        const int e = ebase + j * 512 + t;
        if (e < 2 * NEDGE) {
            const int g = (e >= NEDGE);
            const int ee = e - g * NEDGE;
            const int r = rows[j];
            const int c = g ? col_high[ee] : col_low[ee];
            const float v = g ? val_high[ee] : val_low[ee];
            const int fb = g * NBUCK + (r >> 7);
            const unsigned int pos = base_s[fb] + rank[j];
            if (pos < CAP) {
                uint2 pk;
                pk.x = (unsigned int)c | ((unsigned int)(r & 127) << 16);
                pk.y = (unsigned)__half_as_ushort(__float2half(v));
                packed[(size_t)fb * CAP + pos] = pk;
            }
        }
    }
}

// ---------------------------------------------------------------------------
// K2: fused [sort | gemm] by blockIdx split (R15 structure).
// Sort: row-only counting sort (128 rows, 2-wave scan), compact 4B records
// padded to mult-of-8 per node. rs = start slot; rc = padded_count/4 (even).
// ---------------------------------------------------------------------------
__global__ __launch_bounds__(256)
void sort_gemm_kernel(const uint2* __restrict__ packed,
                      unsigned int* __restrict__ rec4,
                      const unsigned int* __restrict__ gcursor,
                      int* __restrict__ rs, int* __restrict__ rc,
                      const float* __restrict__ x,
                      const float* __restrict__ Wl, const float* __restrict__ Wh,
                      const float* __restrict__ Wm,
                      unsigned short* __restrict__ hl16,
                      unsigned short* __restrict__ hh16,
                      unsigned short* __restrict__ hm16)
{
    __shared__ char smem[27648];   // gemm wt 27648B | sort ~15.9KB
    const int t = threadIdx.x;

    if (blockIdx.x < SORT_BLOCKS) {
        // ------------------------------ sort -------------------------------
        unsigned int*  rec_s = (unsigned int*)smem;            // CAP*4 = 11520
        unsigned char* row_s = (unsigned char*)(rec_s + CAP);  // CAP
        unsigned int*  hist  = (unsigned int*)(row_s + CAP);   // 128
        unsigned int*  offs  = hist + 128;
        unsigned int*  cur   = offs + 128;
        unsigned int*  wsum2 = cur + 128;

        const int fb = blockIdx.x;
        const uint2* __restrict__ seg = packed + (size_t)fb * CAP;
        unsigned int* __restrict__ rout = rec4 + (size_t)fb * CAP;
        int cnt = (int)gcursor[fb];
        if (cnt > CAP) cnt = CAP;

        if (t < 128) { hist[t] = 0u; cur[t] = 0u; }
        __syncthreads();

        for (int i = t; i < cnt; i += 256) {
            const uint2 p = seg[i];
            const unsigned r = (p.x >> 16) & 127u;
            rec_s[i] = (p.x & 0xFFFFu) | (p.y << 16);
            row_s[i] = (unsigned char)r;
            atomicAdd(&hist[r], 1u);
        }
        __syncthreads();

        unsigned pv = 0, xinc = 0;
        if (t < 128) {   // padded counts, 2-wave scan
            pv = (hist[t] + 7u) & ~7u;
            xinc = pv;
#pragma unroll
            for (int d = 1; d < 64; d <<= 1) {
                unsigned y = __shfl_up(xinc, d, 64);
                if ((t & 63) >= d) xinc += y;
            }
            if ((t & 63) == 63) wsum2[t >> 6] = xinc;
        }
        __syncthreads();
        if (t < 128) {
            const unsigned add = (t >= 64) ? wsum2[0] : 0u;
            offs[t] = add + xinc - pv;
        }
        __syncthreads();

        for (int i = t; i < cnt; i += 256) {
            const unsigned r = row_s[i];
            const unsigned pos = offs[r] + atomicAdd(&cur[r], 1u);
            if (pos < CAP) rout[pos] = rec_s[i];
        }
        if (t < 128) {   // pad records {col=0,val=0}
            const unsigned b = offs[t] + hist[t];
            const unsigned e = offs[t] + ((hist[t] + 7u) & ~7u);
            for (unsigned u = b; u < e && u < CAP; ++u) rout[u] = 0u;
        }

        if (t < 128) {
            const int g = (fb >= NBUCK);
            const int node = ((fb - g * NBUCK) << 7) + t;
            if (node < NNODE) {
                const unsigned P = (hist[t] + 7u) & ~7u;
                const int avail = CAP - (int)offs[t];
                int nq = (int)(P >> 2);                          // 4-edge quads, even
                int nqa = avail > 0 ? ((avail >> 2) & ~1) : 0;
                if (nq > nqa) nq = nqa;
                rs[g * NNODE + node] = fb * CAP + (int)offs[t];
                rc[g * NNODE + node] = nq;
            }
        }
    } else {
        // ------------------------------ gemm -------------------------------
        typedef unsigned short wt_t[64][72];
        wt_t* wt = (wt_t*)smem;            // [3][64][72] bf16, 27648B

#pragma unroll 1
        for (int m = 0; m < 3; ++m) {
            const float* __restrict__ W = (m == 0) ? Wl : (m == 1) ? Wh : Wm;
            for (int i = t; i < 4096; i += 256) {
                const int k = i >> 6, c = i & 63;
                wt[m][c][k] = f2bf(W[i]);
            }
        }
        __syncthreads();

        const int wid = t >> 6, lane = t & 63;
        const int node0 = (blockIdx.x - SORT_BLOCKS) * 64 + wid * 16;
        if (node0 >= NNODE) return;
        const int arow = lane & 15;
        const int hi = lane >> 4;

        const float* __restrict__ xr = x + (size_t)(node0 + arow) * 64 + hi * 8;
        const float4 pa0 = *(const float4*)(xr + 0);
        const float4 pa1 = *(const float4*)(xr + 4);
        const float4 pb0 = *(const float4*)(xr + 32);
        const float4 pb1 = *(const float4*)(xr + 36);
        short8v a0, a1;
        a0[0] = (short)f2bf(pa0.x); a0[1] = (short)f2bf(pa0.y);
        a0[2] = (short)f2bf(pa0.z); a0[3] = (short)f2bf(pa0.w);
        a0[4] = (short)f2bf(pa1.x); a0[5] = (short)f2bf(pa1.y);
        a0[6] = (short)f2bf(pa1.z); a0[7] = (short)f2bf(pa1.w);
        a1[0] = (short)f2bf(pb0.x); a1[1] = (short)f2bf(pb0.y);
        a1[2] = (short)f2bf(pb0.z); a1[3] = (short)f2bf(pb0.w);
        a1[4] = (short)f2bf(pb1.x); a1[5] = (short)f2bf(pb1.y);
        a1[6] = (short)f2bf(pb1.z); a1[7] = (short)f2bf(pb1.w);

#pragma unroll 1
        for (int m = 0; m < 3; ++m) {
            unsigned short* __restrict__ H = (m == 0) ? hl16 : (m == 1) ? hh16 : hm16;
            float4v acc0 = {0.f, 0.f, 0.f, 0.f}, acc1 = {0.f, 0.f, 0.f, 0.f};
            float4v acc2 = {0.f, 0.f, 0.f, 0.f}, acc3 = {0.f, 0.f, 0.f, 0.f};

#define DO_CT(CT, ACC)                                                          \
            {                                                                   \
                const short8v b0 = *(const short8v*)&wt[m][CT * 16 + arow][hi * 8]; \
                const short8v b1 = *(const short8v*)&wt[m][CT * 16 + arow][32 + hi * 8]; \
                ACC = __builtin_amdgcn_mfma_f32_16x16x32_bf16(a0, b0, ACC, 0, 0, 0); \
                ACC = __builtin_amdgcn_mfma_f32_16x16x32_bf16(a1, b1, ACC, 0, 0, 0); \
            }
            DO_CT(0, acc0) DO_CT(1, acc1) DO_CT(2, acc2) DO_CT(3, acc3)
#undef DO_CT

            const bool rl = (m == 2);
#define ST_CT(CT, ACC)                                                          \
            {                                                                   \
                _Pragma("unroll")                                               \
                for (int r = 0; r < 4; ++r) {                                   \
                    float v = ACC[r];                                           \
                    if (rl) v = fmaxf(v, 0.f);                                  \
                    H[(size_t)(node0 + hi * 4 + r) * 64 + CT * 16 + arow] =     \
                        __half_as_ushort(__float2half(v));                      \
                }                                                               \
            }
            ST_CT(0, acc0) ST_CT(1, acc1) ST_CT(2, acc2) ST_CT(3, acc3)
#undef ST_CT
        }
    }
}

// ---------------------------------------------------------------------------
// K3: wave-per-node quad-gather spmm + fused finalize.
// 16 lanes/edge, 4B records, packed f16 math. 4-quad main loop (8 records +
// 8 gathers in flight), 2-quad tail (rc even). rc in 4-edge quads.
// Residency 6 waves/SIMD (~84 VGPR cap).
// ---------------------------------------------------------------------------
#define GATH(hg_, rr_) (*(const uint2*)((const char*)(hg_) + (size_t)((((rr_) & 0xFFFFu) << 7) + fb2)))
#define DSWAP(rr_) (((rr_) & 0xFFFF0000u) | ((rr_) >> 16))

__global__ __launch_bounds__(256, 6)
void spmm_finalize_kernel(const unsigned int* __restrict__ rec4,
                          const int* __restrict__ rs, const int* __restrict__ rc,
                          const unsigned short* __restrict__ hl16,
                          const unsigned short* __restrict__ hh16,
                          const unsigned short* __restrict__ hm16,
                          const float* __restrict__ aL, const float* __restrict__ aH,
                          const float* __restrict__ aM, const float* __restrict__ att3,
                          float* __restrict__ out)
{
    const int wid = threadIdx.x >> 6;
    const int lane = threadIdx.x & 63;
    const int sub = lane >> 4;
    const int f4 = (lane & 15) << 2;
    const unsigned fb2 = (unsigned)(f4 * 2);   // byte offset into f16 row
    const int node = blockIdx.x * 4 + wid;
    if (node >= NNODE) return;

    const int sL = __builtin_amdgcn_readfirstlane(rs[node]);
    const int nqL = __builtin_amdgcn_readfirstlane(rc[node]);
    const int sH = __builtin_amdgcn_readfirstlane(rs[NNODE + node]);
    const int nqH = __builtin_amdgcn_readfirstlane(rc[NNODE + node]);
    const unsigned int* __restrict__ segL = rec4 + sL + sub;   // per-lane base
    const unsigned int* __restrict__ segH = rec4 + sH + sub;
    const int nqm = (nqL > nqH) ? nqL : nqH;

    const __half2 hz2 = u_as_h2(0u);
    __half2 aL0a = hz2, aL1a = hz2, aL0b = hz2, aL1b = hz2;
    __half2 aH0a = hz2, aH1a = hz2, aH0b = hz2, aH1b = hz2;

    int q = 0;
#pragma unroll 1
    for (; q + 4 <= nqm; q += 4) {
        const unsigned rL0 = segL[q * 4],      rL1 = segL[q * 4 + 4];
        const unsigned rL2 = segL[q * 4 + 8],  rL3 = segL[q * 4 + 12];
        const unsigned rH0 = segH[q * 4],      rH1 = segH[q * 4 + 4];
        const unsigned rH2 = segH[q * 4 + 8],  rH3 = segH[q * 4 + 12];
        const uint2 uL0 = GATH(hl16, rL0), uL1 = GATH(hl16, rL1);
        const uint2 uL2 = GATH(hl16, rL2), uL3 = GATH(hl16, rL3);
        const uint2 uH0 = GATH(hh16, rH0), uH1 = GATH(hh16, rH1);
        const uint2 uH2 = GATH(hh16, rH2), uH3 = GATH(hh16, rH3);
        __builtin_amdgcn_sched_barrier(0);   // keep all 16 loads issued here
        const __half2 vL0 = u_as_h2((q     < nqL) ? DSWAP(rL0) : 0u);
        const __half2 vL1 = u_as_h2((q + 1 < nqL) ? DSWAP(rL1) : 0u);
        const __half2 vL2 = u_as_h2((q + 2 < nqL) ? DSWAP(rL2) : 0u);
        const __half2 vL3 = u_as_h2((q + 3 < nqL) ? DSWAP(rL3) : 0u);
        const __half2 vH0 = u_as_h2((q     < nqH) ? DSWAP(rH0) : 0u);
        const __half2 vH1 = u_as_h2((q + 1 < nqH) ? DSWAP(rH1) : 0u);
        const __half2 vH2 = u_as_h2((q + 2 < nqH) ? DSWAP(rH2) : 0u);
        const __half2 vH3 = u_as_h2((q + 3 < nqH) ? DSWAP(rH3) : 0u);
        aL0a = __hfma2(u_as_h2(uL0.x), vL0, aL0a);
        aL1a = __hfma2(u_as_h2(uL0.y), vL0, aL1a);
        aL0b = __hfma2(u_as_h2(uL1.x), vL1, aL0b);
        aL1b = __hfma2(u_as_h2(uL1.y), vL1, aL1b);
        aL0a = __hfma2(u_as_h2(uL2.x), vL2, aL0a);
        aL1a = __hfma2(u_as_h2(uL2.y), vL2, aL1a);
        aL0b = __hfma2(u_as_h2(uL3.x), vL3, aL0b);
        aL1b = __hfma2(u_as_h2(uL3.y), vL3, aL1b);
        aH0a = __hfma2(u_as_h2(uH0.x), vH0, aH0a);
        aH1a = __hfma2(u_as_h2(uH0.y), vH0, aH1a);
        aH0b = __hfma2(u_as_h2(uH1.x), vH1, aH0b);
        aH1b = __hfma2(u_as_h2(uH1.y), vH1, aH1b);
        aH0a = __hfma2(u_as_h2(uH2.x), vH2, aH0a);
        aH1a = __hfma2(u_as_h2(uH2.y), vH2, aH1a);
        aH0b = __hfma2(u_as_h2(uH3.x), vH3, aH0b);
        aH1b = __hfma2(u_as_h2(uH3.y), vH3, aH1b);
    }
#pragma unroll 1
    for (; q + 2 <= nqm; q += 2) {
        const unsigned rL0 = segL[q * 4], rL1 = segL[q * 4 + 4];
        const unsigned rH0 = segH[q * 4], rH1 = segH[q * 4 + 4];
        const uint2 uL0 = GATH(hl16, rL0), uL1 = GATH(hl16, rL1);
        const uint2 uH0 = GATH(hh16, rH0), uH1 = GATH(hh16, rH1);
        __builtin_amdgcn_sched_barrier(0);
        const __half2 vL0 = u_as_h2((q     < nqL) ? DSWAP(rL0) : 0u);
        const __half2 vL1 = u_as_h2((q + 1 < nqL) ? DSWAP(rL1) : 0u);
        const __half2 vH0 = u_as_h2((q     < nqH) ? DSWAP(rH0) : 0u);
        const __half2 vH1 = u_as_h2((q + 1 < nqH) ? DSWAP(rH1) : 0u);
        aL0a = __hfma2(u_as_h2(uL0.x), vL0, aL0a);
        aL1a = __hfma2(u_as_h2(uL0.y), vL0, aL1a);
        aL0b = __hfma2(u_as_h2(uL1.x), vL1, aL0b);
        aL1b = __hfma2(u_as_h2(uL1.y), vL1, aL1b);
        aH0a = __hfma2(u_as_h2(uH0.x), vH0, aH0a);
        aH1a = __hfma2(u_as_h2(uH0.y), vH0, aH1a);
        aH0b = __hfma2(u_as_h2(uH1.x), vH1, aH0b);
        aH1b = __hfma2(u_as_h2(uH1.y), vH1, aH1b);
    }

    float lx = __low2float(aL0a) + __low2float(aL0b);
    float ly = __high2float(aL0a) + __high2float(aL0b);
    float lz = __low2float(aL1a) + __low2float(aL1b);
    float lw = __high2float(aL1a) + __high2float(aL1b);
    float hx = __low2float(aH0a) + __low2float(aH0b);
    float hy = __high2float(aH0a) + __high2float(aH0b);
    float hz = __low2float(aH1a) + __low2float(aH1b);
    float hw = __high2float(aH1a) + __high2float(aH1b);

    lx += __shfl_xor(lx, 16, 64); ly += __shfl_xor(ly, 16, 64);
    lz += __shfl_xor(lz, 16, 64); lw += __shfl_xor(lw, 16, 64);
    hx += __shfl_xor(hx, 16, 64); hy += __shfl_xor(hy, 16, 64);
    hz += __shfl_xor(hz, 16, 64); hw += __shfl_xor(hw, 16, 64);
    lx += __shfl_xor(lx, 32, 64); ly += __shfl_xor(ly, 32, 64);
    lz += __shfl_xor(lz, 32, 64); lw += __shfl_xor(lw, 32, 64);
    hx += __shfl_xor(hx, 32, 64); hy += __shfl_xor(hy, 32, 64);
    hz += __shfl_xor(hz, 32, 64); hw += __shfl_xor(hw, 32, 64);

    const float olx = fmaxf(lx, 0.f), oly = fmaxf(ly, 0.f);
    const float olz = fmaxf(lz, 0.f), olw = fmaxf(lw, 0.f);
    const float ohx = fmaxf(hx, 0.f), ohy = fmaxf(hy, 0.f);
    const float ohz = fmaxf(hz, 0.f), ohw = fmaxf(hw, 0.f);

    const uint2 om2 = *(const uint2*)&hm16[(size_t)node * 64 + f4];
    const float omx = __low2float(u_as_h2(om2.x));
    const float omy = __high2float(u_as_h2(om2.x));
    const float omz = __low2float(u_as_h2(om2.y));
    const float omw = __high2float(u_as_h2(om2.y));

    const float4 aL4 = *(const float4*)&aL[f4];
    const float4 aH4 = *(const float4*)&aH[f4];
    const float4 aM4 = *(const float4*)&aM[f4];

    float f0 = olx * aL4.x + oly * aL4.y + olz * aL4.z + olw * aL4.w;
    float f1 = ohx * aH4.x + ohy * aH4.y + ohz * aH4.z + ohw * aH4.w;
    float f2 = omx * aM4.x + omy * aM4.y + omz * aM4.z + omw * aM4.w;
#pragma unroll
    for (int msk = 1; msk < 16; msk <<= 1) {
        f0 += __shfl_xor(f0, msk, 64);
        f1 += __shfl_xor(f1, msk, 64);
        f2 += __shfl_xor(f2, msk, 64);
    }
    const float s0 = 1.f / (1.f + __expf(-f0));
    const float s1 = 1.f / (1.f + __expf(-f1));
    const float s2 = 1.f / (1.f + __expf(-f2));
    const float invT = 1.f / 3.f;
    const float l0g = (s0 * att3[0] + s1 * att3[3] + s2 * att3[6]) * invT;
    const float l1g = (s0 * att3[1] + s1 * att3[4] + s2 * att3[7]) * invT;
    const float l2g = (s0 * att3[2] + s1 * att3[5] + s2 * att3[8]) * invT;
    const float mx = fmaxf(l0g, fmaxf(l1g, l2g));
    const float e0 = __expf(l0g - mx);
    const float e1 = __expf(l1g - mx);
    const float e2 = __expf(l2g - mx);
    const float inv = 1.f / (e0 + e1 + e2);
    const float wl = 3.f * inv * e0, wh = 3.f * inv * e1, wm = 3.f * inv * e2;

    if (lane < 16) {
        float4 o;
        o.x = wl * olx + wh * ohx + wm * omx;
        o.y = wl * oly + wh * ohy + wm * omy;
        o.z = wl * olz + wh * ohz + wm * omz;
        o.w = wl * olw + wh * ohw + wm * omw;
        *(float4*)&out[(size_t)node * 64 + f4] = o;
    }
}

extern "C" void kernel_launch(void* const* d_in, const int* in_sizes, int n_in,
                              void* d_out, int out_size, void* d_ws, size_t ws_size,
                              hipStream_t stream)
{
    const float* x        = (const float*)d_in[0];
    const int*   row_low  = (const int*)  d_in[1];
    const int*   col_low  = (const int*)  d_in[2];
    const float* val_low  = (const float*)d_in[3];
    const int*   row_high = (const int*)  d_in[4];
    const int*   col_high = (const int*)  d_in[5];
    const float* val_high = (const float*)d_in[6];
    const float* W_low    = (const float*)d_in[7];
    const float* W_high   = (const float*)d_in[8];
    const float* W_mlp    = (const float*)d_in[9];
    const float* a_low    = (const float*)d_in[10];
    const float* a_high   = (const float*)d_in[11];
    const float* a_mlp    = (const float*)d_in[12];
    const float* att3     = (const float*)d_in[13];
    float* out = (float*)d_out;

    const size_t NM = (size_t)NNODE * 64;
    const size_t NSLOT = (size_t)2 * NBUCK * CAP;

    unsigned short* hl16    = (unsigned short*)d_ws;          // N*64 f16
    unsigned short* hh16    = hl16 + NM;                      // N*64 f16
    unsigned short* hm16    = hh16 + NM;                      // N*64 f16
    uint2*          packed  = (uint2*)(hm16 + NM);            // NSLOT uint2
    unsigned int*   rec4    = (unsigned int*)(packed + NSLOT);// NSLOT u32
    unsigned int*   gcursor = rec4 + NSLOT;                   // 2*NBUCK
    int*            rs      = (int*)(gcursor + 2 * NBUCK);    // 2*N
    int*            rc      = rs + 2 * NNODE;                 // 2*N

    zero_kernel<<<(2 * NBUCK + 255) / 256, 256, 0, stream>>>(gcursor);

    scatter_kernel<<<(2 * NEDGE + 8191) / 8192, 512, 0, stream>>>(
        row_low, col_low, val_low, row_high, col_high, val_high, gcursor, packed);

    sort_gemm_kernel<<<SORT_BLOCKS + GEMM_BLOCKS, 256, 0, stream>>>(
        packed, rec4, gcursor, rs, rc,
        x, W_low, W_high, W_mlp, hl16, hh16, hm16);

    spmm_finalize_kernel<<<(NNODE + 3) / 4, 256, 0, stream>>>(
        rec4, rs, rc, hl16, hh16, hm16, a_low, a_high, a_mlp, att3, out);
}